// Round 1
// baseline (1414.638 us; speedup 1.0000x reference)
//
#include <hip/hip_runtime.h>
#include <hip/hip_bf16.h>

// GraphSparseConvolution on MI355X.
// Round 0: baseline — atomic scatter for both SpMMs, fused sparse dropout,
// mask-format autodetect, final ReLU pass.
//
// ws layout: [0..256): flags (2 ints used)   [256 ...): h [N x 128] f32 (51.2 MB)

static constexpr int O_DIM = 128;
static constexpr float KEEP_INV = 1.0f / 0.9f;  // 1/keep_prob

// ---------------------------------------------------------------------------
// Detect how the harness materialized the bool keep_mask.
// flags[0] = 0 iff every scanned 32-bit word is in {0,1}        -> int32 mask
// flags[1] = 0 iff every scanned 32-bit word is in {0,1.0f bits} -> f32 mask
// else byte (uint8) mask. Deterministic: pure function of input bytes.
__global__ void detect_mask_kernel(const unsigned int* __restrict__ w, int nwords,
                                   int* __restrict__ flags) {
    __shared__ int sA[256];
    __shared__ int sB[256];
    int t = threadIdx.x;
    int violA = 0, violB = 0;
    for (int i = t; i < nwords; i += 256) {
        unsigned int x = w[i];
        violA |= (x > 1u) ? 1 : 0;
        violB |= (x != 0u && x != 0x3F800000u) ? 1 : 0;
    }
    sA[t] = violA; sB[t] = violB;
    __syncthreads();
    for (int s = 128; s > 0; s >>= 1) {
        if (t < s) { sA[t] |= sA[t + s]; sB[t] |= sB[t + s]; }
        __syncthreads();
    }
    if (t == 0) { flags[0] = sA[0]; flags[1] = sB[0]; }
}

// ---------------------------------------------------------------------------
// SpMM1: h[x_rows[e], :] += dropout(x_vals[e]) * kernel[x_cols[e], :]
// 128 threads per edge; kernel matrix is 131 KB -> L2 hot.
__global__ void spmm1_kernel(const float* __restrict__ xv,
                             const int* __restrict__ xr,
                             const int* __restrict__ xc,
                             const void* __restrict__ mask,
                             const float* __restrict__ kern,
                             const int* __restrict__ flags,
                             float* __restrict__ h,
                             int nnz) {
    long long gid = (long long)blockIdx.x * blockDim.x + threadIdx.x;
    int e = (int)(gid >> 7);
    if (e >= nnz) return;
    int o = (int)(gid & 127);
    bool keep;
    if (flags[0] == 0)      keep = ((const int*)mask)[e] != 0;
    else if (flags[1] == 0) keep = ((const float*)mask)[e] != 0.0f;
    else                    keep = ((const unsigned char*)mask)[e] != 0;
    if (!keep) return;                       // 10% of edges: whole group skips
    float w = xv[e] * KEEP_INV;
    int r = xr[e];
    int c = xc[e];
    atomicAdd(&h[(long long)r * O_DIM + o], w * kern[c * O_DIM + o]);
}

// ---------------------------------------------------------------------------
// SpMM2: out[adj_rows[e], :] += adj_vals[e] * h[adj_cols[e], :]
__global__ void spmm2_kernel(const float* __restrict__ av,
                             const int* __restrict__ ar,
                             const int* __restrict__ ac,
                             const float* __restrict__ h,
                             float* __restrict__ out,
                             int nnz) {
    long long gid = (long long)blockIdx.x * blockDim.x + threadIdx.x;
    int e = (int)(gid >> 7);
    if (e >= nnz) return;
    int o = (int)(gid & 127);
    float w = av[e];
    int r = ar[e];
    int c = ac[e];
    atomicAdd(&out[(long long)r * O_DIM + o], w * h[(long long)c * O_DIM + o]);
}

// ---------------------------------------------------------------------------
__global__ void relu_kernel(float* __restrict__ out, int n4) {
    int stride = gridDim.x * blockDim.x;
    float4* p = (float4*)out;
    for (int i = blockIdx.x * blockDim.x + threadIdx.x; i < n4; i += stride) {
        float4 v = p[i];
        v.x = fmaxf(v.x, 0.0f);
        v.y = fmaxf(v.y, 0.0f);
        v.z = fmaxf(v.z, 0.0f);
        v.w = fmaxf(v.w, 0.0f);
        p[i] = v;
    }
}

// ---------------------------------------------------------------------------
extern "C" void kernel_launch(void* const* d_in, const int* in_sizes, int n_in,
                              void* d_out, int out_size, void* d_ws, size_t ws_size,
                              hipStream_t stream) {
    const float* x_vals   = (const float*)d_in[0];
    const float* kern     = (const float*)d_in[1];   // [256 x 128]
    const float* adj_vals = (const float*)d_in[2];
    const int*   x_rows   = (const int*)d_in[3];
    const int*   x_cols   = (const int*)d_in[4];
    const int*   adj_rows = (const int*)d_in[5];
    const int*   adj_cols = (const int*)d_in[6];
    const void*  mask     = d_in[7];

    const int nnz_x = in_sizes[0];
    const int nnz_a = in_sizes[2];
    const int n_nodes = out_size / O_DIM;   // 100000

    float* out = (float*)d_out;
    int*   flags = (int*)d_ws;
    float* h = (float*)((char*)d_ws + 256);   // needs ~51.2 MB of ws

    // 1. mask format detection (tiny, one block)
    int scan_words = nnz_x / 4;                 // safe under every candidate layout
    if (scan_words > 16384) scan_words = 16384;
    detect_mask_kernel<<<1, 256, 0, stream>>>((const unsigned int*)mask, scan_words, flags);

    // 2. zero accumulators (graph-capture-safe)
    hipMemsetAsync(h, 0, (size_t)n_nodes * O_DIM * sizeof(float), stream);
    hipMemsetAsync(out, 0, (size_t)out_size * sizeof(float), stream);

    // 3. SpMM1 (dropout fused)
    {
        long long threads = (long long)nnz_x * O_DIM;
        int blocks = (int)((threads + 255) / 256);
        spmm1_kernel<<<blocks, 256, 0, stream>>>(x_vals, x_rows, x_cols, mask,
                                                 kern, flags, h, nnz_x);
    }

    // 4. SpMM2
    {
        long long threads = (long long)nnz_a * O_DIM;
        int blocks = (int)((threads + 255) / 256);
        spmm2_kernel<<<blocks, 256, 0, stream>>>(adj_vals, adj_rows, adj_cols,
                                                 h, out, nnz_a);
    }

    // 5. ReLU in place on d_out
    {
        int n4 = out_size / 4;
        int blocks = (n4 + 255) / 256;
        if (blocks > 2048) blocks = 2048;
        relu_kernel<<<blocks, 256, 0, stream>>>(out, n4);
    }
}

// Round 2
// 722.803 us; speedup vs baseline: 1.9572x; 1.9572x over previous
//
#include <hip/hip_runtime.h>
#include <hip/hip_bf16.h>

// GraphSparseConvolution on MI355X.
// Round 1: device-built CSR (count -> scan -> scatter) for BOTH sparse
// matrices, then per-row register accumulation with a single write per
// output element. Dropout fused into X-scatter; ReLU fused into spmm2 write.
// Fallback to round-0 atomic path if ws_size is too small for CSR buffers.

static constexpr int O_DIM = 128;
static constexpr float KEEP_INV = 1.0f / 0.9f;  // 1/keep_prob

// ---------------------------------------------------------------------------
// Detect how the harness materialized the bool keep_mask (int32/f32/uint8).
__global__ void detect_mask_kernel(const unsigned int* __restrict__ w, int nwords,
                                   int* __restrict__ flags) {
    __shared__ int sA[256];
    __shared__ int sB[256];
    int t = threadIdx.x;
    int violA = 0, violB = 0;
    for (int i = t; i < nwords; i += 256) {
        unsigned int x = w[i];
        violA |= (x > 1u) ? 1 : 0;
        violB |= (x != 0u && x != 0x3F800000u) ? 1 : 0;
    }
    sA[t] = violA; sB[t] = violB;
    __syncthreads();
    for (int s = 128; s > 0; s >>= 1) {
        if (t < s) { sA[t] |= sA[t + s]; sB[t] |= sB[t + s]; }
        __syncthreads();
    }
    if (t == 0) { flags[0] = sA[0]; flags[1] = sB[0]; }
}

// ---------------------------------------------------------------------------
// Histogram of destination rows.
__global__ void count_kernel(const int* __restrict__ rows, int nnz,
                             int* __restrict__ counts) {
    int stride = gridDim.x * blockDim.x;
    for (int i = blockIdx.x * blockDim.x + threadIdx.x; i < nnz; i += stride)
        atomicAdd(&counts[rows[i]], 1);
}

// ---------------------------------------------------------------------------
// Single-block exclusive scan of `counts[0..n)` -> row_start[0..n].
// 1024 threads, 4 elements/thread/chunk (4096 per chunk), shfl wave scan.
__global__ __launch_bounds__(1024) void scan_kernel(const int* __restrict__ counts,
                                                    int* __restrict__ row_start,
                                                    int n) {
    __shared__ int wsum[16];
    __shared__ int carry_s;
    const int t = threadIdx.x;
    const int lane = t & 63, wid = t >> 6;
    if (t == 0) carry_s = 0;
    __syncthreads();
    for (int base = 0; base < n; base += 4096) {
        int i0 = base + t * 4;
        int v0 = (i0 + 0 < n) ? counts[i0 + 0] : 0;
        int v1 = (i0 + 1 < n) ? counts[i0 + 1] : 0;
        int v2 = (i0 + 2 < n) ? counts[i0 + 2] : 0;
        int v3 = (i0 + 3 < n) ? counts[i0 + 3] : 0;
        int tsum = v0 + v1 + v2 + v3;
        int s = tsum;
        #pragma unroll
        for (int d = 1; d < 64; d <<= 1) {
            int up = __shfl_up(s, d, 64);
            if (lane >= d) s += up;
        }
        if (lane == 63) wsum[wid] = s;
        __syncthreads();
        int woff = 0;
        for (int w = 0; w < wid; ++w) woff += wsum[w];
        int carry = carry_s;
        int excl = carry + woff + (s - tsum);
        if (i0 + 0 < n) row_start[i0 + 0] = excl;
        if (i0 + 1 < n) row_start[i0 + 1] = excl + v0;
        if (i0 + 2 < n) row_start[i0 + 2] = excl + v0 + v1;
        if (i0 + 3 < n) row_start[i0 + 3] = excl + v0 + v1 + v2;
        __syncthreads();
        if (t == 1023) carry_s = carry + woff + s;
        __syncthreads();
    }
    if (t == 0) row_start[n] = carry_s;
}

// ---------------------------------------------------------------------------
// Scatter X edges into row-sorted order; dropout fused (masked -> value 0).
__global__ void scatter_x_kernel(const float* __restrict__ xv,
                                 const int* __restrict__ xr,
                                 const int* __restrict__ xc,
                                 const void* __restrict__ mask,
                                 const int* __restrict__ flags,
                                 int* __restrict__ cursor,
                                 int* __restrict__ cols_s,
                                 float* __restrict__ vals_s,
                                 int nnz) {
    int stride = gridDim.x * blockDim.x;
    int f0 = flags[0], f1 = flags[1];
    for (int i = blockIdx.x * blockDim.x + threadIdx.x; i < nnz; i += stride) {
        int r = xr[i];
        int pos = atomicAdd(&cursor[r], 1);
        bool keep;
        if (f0 == 0)      keep = ((const int*)mask)[i] != 0;
        else if (f1 == 0) keep = ((const float*)mask)[i] != 0.0f;
        else              keep = ((const unsigned char*)mask)[i] != 0;
        cols_s[pos] = xc[i];
        vals_s[pos] = keep ? xv[i] * KEEP_INV : 0.0f;
    }
}

__global__ void scatter_a_kernel(const float* __restrict__ av,
                                 const int* __restrict__ ar,
                                 const int* __restrict__ ac,
                                 int* __restrict__ cursor,
                                 int* __restrict__ cols_s,
                                 float* __restrict__ vals_s,
                                 int nnz) {
    int stride = gridDim.x * blockDim.x;
    for (int i = blockIdx.x * blockDim.x + threadIdx.x; i < nnz; i += stride) {
        int r = ar[i];
        int pos = atomicAdd(&cursor[r], 1);
        cols_s[pos] = ac[i];
        vals_s[pos] = av[i];
    }
}

// ---------------------------------------------------------------------------
// CSR SpMM: one 128-thread block per output row; register accumulate;
// single write per element. src is a [*,128] f32 table.
template <bool RELU>
__global__ __launch_bounds__(128) void spmm_csr_kernel(const int* __restrict__ row_start,
                                                       const int* __restrict__ cols,
                                                       const float* __restrict__ vals,
                                                       const float* __restrict__ src,
                                                       float* __restrict__ dst) {
    int r = blockIdx.x;
    int t = threadIdx.x;
    int j = row_start[r], end = row_start[r + 1];
    float acc = 0.0f;
    for (; j < end; ++j) {
        int c = cols[j];
        float v = vals[j];
        acc = fmaf(v, src[(long long)c * O_DIM + t], acc);
    }
    if (RELU) acc = fmaxf(acc, 0.0f);
    dst[(long long)r * O_DIM + t] = acc;
}

// ---------------------------------------------------------------------------
// Round-0 fallback kernels (used only if ws_size too small for CSR buffers).
__global__ void spmm1_atomic_kernel(const float* __restrict__ xv,
                                    const int* __restrict__ xr,
                                    const int* __restrict__ xc,
                                    const void* __restrict__ mask,
                                    const float* __restrict__ kern,
                                    const int* __restrict__ flags,
                                    float* __restrict__ h, int nnz) {
    long long gid = (long long)blockIdx.x * blockDim.x + threadIdx.x;
    int e = (int)(gid >> 7);
    if (e >= nnz) return;
    int o = (int)(gid & 127);
    bool keep;
    if (flags[0] == 0)      keep = ((const int*)mask)[e] != 0;
    else if (flags[1] == 0) keep = ((const float*)mask)[e] != 0.0f;
    else                    keep = ((const unsigned char*)mask)[e] != 0;
    if (!keep) return;
    atomicAdd(&h[(long long)xr[e] * O_DIM + o], xv[e] * KEEP_INV * kern[xc[e] * O_DIM + o]);
}

__global__ void spmm2_atomic_kernel(const float* __restrict__ av,
                                    const int* __restrict__ ar,
                                    const int* __restrict__ ac,
                                    const float* __restrict__ h,
                                    float* __restrict__ out, int nnz) {
    long long gid = (long long)blockIdx.x * blockDim.x + threadIdx.x;
    int e = (int)(gid >> 7);
    if (e >= nnz) return;
    int o = (int)(gid & 127);
    atomicAdd(&out[(long long)ar[e] * O_DIM + o], av[e] * h[(long long)ac[e] * O_DIM + o]);
}

__global__ void relu_kernel(float* __restrict__ out, int n4) {
    int stride = gridDim.x * blockDim.x;
    float4* p = (float4*)out;
    for (int i = blockIdx.x * blockDim.x + threadIdx.x; i < n4; i += stride) {
        float4 v = p[i];
        v.x = fmaxf(v.x, 0.0f); v.y = fmaxf(v.y, 0.0f);
        v.z = fmaxf(v.z, 0.0f); v.w = fmaxf(v.w, 0.0f);
        p[i] = v;
    }
}

// ---------------------------------------------------------------------------
static inline size_t align256(size_t x) { return (x + 255) & ~(size_t)255; }

extern "C" void kernel_launch(void* const* d_in, const int* in_sizes, int n_in,
                              void* d_out, int out_size, void* d_ws, size_t ws_size,
                              hipStream_t stream) {
    const float* x_vals   = (const float*)d_in[0];
    const float* kern     = (const float*)d_in[1];   // [256 x 128]
    const float* adj_vals = (const float*)d_in[2];
    const int*   x_rows   = (const int*)d_in[3];
    const int*   x_cols   = (const int*)d_in[4];
    const int*   adj_rows = (const int*)d_in[5];
    const int*   adj_cols = (const int*)d_in[6];
    const void*  mask     = d_in[7];

    const int nnz_x = in_sizes[0];
    const int nnz_a = in_sizes[2];
    const int n_nodes = out_size / O_DIM;

    float* out = (float*)d_out;

    // ---- ws carve-up ----
    size_t off = 0;
    int* flags = (int*)d_ws;                    off = align256(off + 2 * sizeof(int));
    size_t o_xrs = off;                         off = align256(off + (size_t)(n_nodes + 1) * 4);
    size_t o_xcur = off;                        off = align256(off + (size_t)n_nodes * 4);
    size_t o_ars = off;                         off = align256(off + (size_t)(n_nodes + 1) * 4);
    size_t o_acur = off;                        off = align256(off + (size_t)n_nodes * 4);
    size_t o_xcols = off;                       off = align256(off + (size_t)nnz_x * 4);
    size_t o_xvals = off;                       off = align256(off + (size_t)nnz_x * 4);
    size_t o_acols = off;                       off = align256(off + (size_t)nnz_a * 4);
    size_t o_avals = off;                       off = align256(off + (size_t)nnz_a * 4);
    size_t o_h = off;                           off = align256(off + (size_t)n_nodes * O_DIM * 4);
    const bool csr_ok = (off <= ws_size);

    char* ws = (char*)d_ws;

    // mask format detection (needed by both paths)
    int scan_words = nnz_x / 4;
    if (scan_words > 16384) scan_words = 16384;
    detect_mask_kernel<<<1, 256, 0, stream>>>((const unsigned int*)mask, scan_words, flags);

    if (csr_ok) {
        int* x_rs   = (int*)(ws + o_xrs);
        int* x_cur  = (int*)(ws + o_xcur);
        int* a_rs   = (int*)(ws + o_ars);
        int* a_cur  = (int*)(ws + o_acur);
        int* x_cols_s = (int*)(ws + o_xcols);
        float* x_vals_s = (float*)(ws + o_xvals);
        int* a_cols_s = (int*)(ws + o_acols);
        float* a_vals_s = (float*)(ws + o_avals);
        float* h = (float*)(ws + o_h);

        // 1. histogram (counts accumulate in the cursor arrays)
        hipMemsetAsync(x_cur, 0, (size_t)n_nodes * 4, stream);
        hipMemsetAsync(a_cur, 0, (size_t)n_nodes * 4, stream);
        {
            int blocks = (nnz_x + 255) / 256; if (blocks > 2048) blocks = 2048;
            count_kernel<<<blocks, 256, 0, stream>>>(x_rows, nnz_x, x_cur);
            blocks = (nnz_a + 255) / 256; if (blocks > 2048) blocks = 2048;
            count_kernel<<<blocks, 256, 0, stream>>>(adj_rows, nnz_a, a_cur);
        }
        // 2. exclusive scans
        scan_kernel<<<1, 1024, 0, stream>>>(x_cur, x_rs, n_nodes);
        scan_kernel<<<1, 1024, 0, stream>>>(a_cur, a_rs, n_nodes);
        // 3. reset cursors to row starts
        hipMemcpyAsync(x_cur, x_rs, (size_t)n_nodes * 4, hipMemcpyDeviceToDevice, stream);
        hipMemcpyAsync(a_cur, a_rs, (size_t)n_nodes * 4, hipMemcpyDeviceToDevice, stream);
        // 4. scatter into row-sorted order (dropout fused into X values)
        {
            int blocks = (nnz_x + 255) / 256; if (blocks > 2048) blocks = 2048;
            scatter_x_kernel<<<blocks, 256, 0, stream>>>(x_vals, x_rows, x_cols, mask,
                                                         flags, x_cur, x_cols_s, x_vals_s, nnz_x);
            blocks = (nnz_a + 255) / 256; if (blocks > 2048) blocks = 2048;
            scatter_a_kernel<<<blocks, 256, 0, stream>>>(adj_vals, adj_rows, adj_cols,
                                                         a_cur, a_cols_s, a_vals_s, nnz_a);
        }
        // 5. SpMM1: h = dropout(X) @ kernel   (single write per element)
        spmm_csr_kernel<false><<<n_nodes, 128, 0, stream>>>(x_rs, x_cols_s, x_vals_s, kern, h);
        // 6. SpMM2 + ReLU: out = relu(adj @ h)
        spmm_csr_kernel<true><<<n_nodes, 128, 0, stream>>>(a_rs, a_cols_s, a_vals_s, h, out);
    } else {
        // ---- fallback: round-0 atomic path (needs only h + flags in ws) ----
        float* h = (float*)(ws + 256);
        hipMemsetAsync(h, 0, (size_t)n_nodes * O_DIM * 4, stream);
        hipMemsetAsync(out, 0, (size_t)out_size * 4, stream);
        {
            long long threads = (long long)nnz_x * O_DIM;
            int blocks = (int)((threads + 255) / 256);
            spmm1_atomic_kernel<<<blocks, 256, 0, stream>>>(x_vals, x_rows, x_cols, mask,
                                                            kern, flags, h, nnz_x);
            threads = (long long)nnz_a * O_DIM;
            blocks = (int)((threads + 255) / 256);
            spmm2_atomic_kernel<<<blocks, 256, 0, stream>>>(adj_vals, adj_rows, adj_cols,
                                                            h, out, nnz_a);
        }
        int n4 = out_size / 4;
        int blocks = (n4 + 255) / 256; if (blocks > 2048) blocks = 2048;
        relu_kernel<<<blocks, 256, 0, stream>>>(out, n4);
    }
}

// Round 3
// 614.310 us; speedup vs baseline: 2.3028x; 1.1766x over previous
//
#include <hip/hip_runtime.h>
#include <hip/hip_bf16.h>

// GraphSparseConvolution on MI355X.
// Round 2: (a) h stored as f16 -> halves spmm2 gather bytes + better L2 hit,
// (b) fused CSR build: one histogram over both matrices (concatenated bins),
//     3-phase multi-block scan (replaces two serial single-block scans and
//     both cursor memcpys), one fused scatter writing packed {col,val} int2,
// (c) software-pipelined spmm inner loop.
// Fallback to atomic path if ws too small.

static constexpr int O_DIM = 128;
static constexpr float KEEP_INV = 1.0f / 0.9f;  // 1/keep_prob

using half_t = _Float16;

// ---------------------------------------------------------------------------
// Detect how the harness materialized the bool keep_mask (int32/f32/uint8).
__global__ void detect_mask_kernel(const unsigned int* __restrict__ w, int nwords,
                                   int* __restrict__ flags) {
    __shared__ int sA[256];
    __shared__ int sB[256];
    int t = threadIdx.x;
    int violA = 0, violB = 0;
    for (int i = t; i < nwords; i += 256) {
        unsigned int x = w[i];
        violA |= (x > 1u) ? 1 : 0;
        violB |= (x != 0u && x != 0x3F800000u) ? 1 : 0;
    }
    sA[t] = violA; sB[t] = violB;
    __syncthreads();
    for (int s = 128; s > 0; s >>= 1) {
        if (t < s) { sA[t] |= sA[t + s]; sB[t] |= sB[t + s]; }
        __syncthreads();
    }
    if (t == 0) { flags[0] = sA[0]; flags[1] = sB[0]; }
}

// ---------------------------------------------------------------------------
// Fused histogram: bins [0,n_nodes) for X rows, [n_nodes, 2*n_nodes) for adj.
__global__ void count_both_kernel(const int* __restrict__ xr, int nnz_x,
                                  const int* __restrict__ ar, int nnz_a,
                                  int n_nodes, int* __restrict__ cnt) {
    int stride = gridDim.x * blockDim.x;
    int tot = nnz_x + nnz_a;
    for (int i = blockIdx.x * blockDim.x + threadIdx.x; i < tot; i += stride) {
        int bin = (i < nnz_x) ? xr[i] : (n_nodes + ar[i - nnz_x]);
        atomicAdd(&cnt[bin], 1);
    }
}

// ---------------------------------------------------------------------------
// 3-phase exclusive scan over cnt[0..n) -> S[0..n], plus cursor copy.
static constexpr int SCAN_BS = 256;
static constexpr int SCAN_IPT = 8;
static constexpr int SCAN_CHUNK = SCAN_BS * SCAN_IPT;  // 2048

__global__ __launch_bounds__(SCAN_BS) void scan_partial_kernel(const int* __restrict__ cnt,
                                                               int n, int* __restrict__ bsums) {
    int b = blockIdx.x, t = threadIdx.x;
    int lane = t & 63, wid = t >> 6;
    __shared__ int wsum[SCAN_BS / 64];
    int base = b * SCAN_CHUNK + t * SCAN_IPT;
    int s = 0;
    #pragma unroll
    for (int k = 0; k < SCAN_IPT; ++k) {
        int i = base + k;
        s += (i < n) ? cnt[i] : 0;
    }
    #pragma unroll
    for (int d = 1; d < 64; d <<= 1) s += __shfl_xor(s, d, 64);
    if (lane == 0) wsum[wid] = s;
    __syncthreads();
    if (t == 0) {
        int tot = 0;
        #pragma unroll
        for (int w = 0; w < SCAN_BS / 64; ++w) tot += wsum[w];
        bsums[b] = tot;
    }
}

// Single block: exclusive-scan bsums[0..nb) in place; write total sentinel.
__global__ __launch_bounds__(1024) void scan_blocksums_kernel(int* __restrict__ bsums, int nb,
                                                              int* __restrict__ sentinel) {
    __shared__ int wsum[16];
    int t = threadIdx.x, lane = t & 63, wid = t >> 6;
    int v = (t < nb) ? bsums[t] : 0;
    int s = v;
    #pragma unroll
    for (int d = 1; d < 64; d <<= 1) {
        int u = __shfl_up(s, d, 64);
        if (lane >= d) s += u;
    }
    if (lane == 63) wsum[wid] = s;
    __syncthreads();
    int woff = 0;
    for (int w = 0; w < wid; ++w) woff += wsum[w];
    if (t < nb) bsums[t] = woff + s - v;      // exclusive
    if (t == 1023) *sentinel = woff + s;      // grand total
}

__global__ __launch_bounds__(SCAN_BS) void scan_final_kernel(const int* __restrict__ cnt, int n,
                                                             const int* __restrict__ bsums,
                                                             int* __restrict__ S,
                                                             int* __restrict__ cursor) {
    __shared__ int wsum[SCAN_BS / 64];
    int b = blockIdx.x, t = threadIdx.x;
    int lane = t & 63, wid = t >> 6;
    int base = b * SCAN_CHUNK + t * SCAN_IPT;
    int v[SCAN_IPT];
    int tsum = 0;
    #pragma unroll
    for (int k = 0; k < SCAN_IPT; ++k) {
        int i = base + k;
        v[k] = (i < n) ? cnt[i] : 0;
        tsum += v[k];
    }
    int s = tsum;
    #pragma unroll
    for (int d = 1; d < 64; d <<= 1) {
        int u = __shfl_up(s, d, 64);
        if (lane >= d) s += u;
    }
    if (lane == 63) wsum[wid] = s;
    __syncthreads();
    int woff = 0;
    for (int w = 0; w < wid; ++w) woff += wsum[w];
    int excl = bsums[b] + woff + (s - tsum);
    #pragma unroll
    for (int k = 0; k < SCAN_IPT; ++k) {
        int i = base + k;
        if (i < n) { S[i] = excl; cursor[i] = excl; }
        excl += v[k];
    }
}

// ---------------------------------------------------------------------------
// Fused scatter into row-sorted packed {col, val_bits} records.
// Adj positions come pre-offset by nnz_x via the concatenated scan.
__global__ void scatter_both_kernel(const float* __restrict__ xv,
                                    const int* __restrict__ xr,
                                    const int* __restrict__ xc,
                                    const void* __restrict__ mask,
                                    const int* __restrict__ flags,
                                    const float* __restrict__ av,
                                    const int* __restrict__ ar,
                                    const int* __restrict__ ac,
                                    int nnz_x, int nnz_a, int n_nodes,
                                    int* __restrict__ cursor,
                                    int2* __restrict__ packed) {
    int stride = gridDim.x * blockDim.x;
    int tot = nnz_x + nnz_a;
    int f0 = flags[0], f1 = flags[1];
    for (int i = blockIdx.x * blockDim.x + threadIdx.x; i < tot; i += stride) {
        if (i < nnz_x) {
            int r = xr[i];
            int pos = atomicAdd(&cursor[r], 1);
            bool keep;
            if (f0 == 0)      keep = ((const int*)mask)[i] != 0;
            else if (f1 == 0) keep = ((const float*)mask)[i] != 0.0f;
            else              keep = ((const unsigned char*)mask)[i] != 0;
            float v = keep ? xv[i] * KEEP_INV : 0.0f;
            packed[pos] = make_int2(xc[i], __float_as_int(v));
        } else {
            int e = i - nnz_x;
            int r = ar[e];
            int pos = atomicAdd(&cursor[n_nodes + r], 1);
            packed[pos] = make_int2(ac[e], __float_as_int(av[e]));
        }
    }
}

// ---------------------------------------------------------------------------
// CSR SpMM: one 128-thread block per output row; software-pipelined loop;
// single write per element.
template <typename SRC_T, typename DST_T, bool RELU>
__global__ __launch_bounds__(128) void spmm_csr_kernel(const int* __restrict__ rs,
                                                       const int2* __restrict__ packed,
                                                       const SRC_T* __restrict__ src,
                                                       DST_T* __restrict__ dst) {
    int r = blockIdx.x;
    int t = threadIdx.x;
    int j = rs[r], end = rs[r + 1];
    float acc = 0.0f;
    if (j < end) {
        int2 e = packed[j];
        int c = e.x; float v = __int_as_float(e.y);
        float s = (float)src[(long long)c * O_DIM + t];
        for (++j; j < end; ++j) {
            int2 e1 = packed[j];
            int c1 = e1.x; float v1 = __int_as_float(e1.y);
            float s1 = (float)src[(long long)c1 * O_DIM + t];
            acc = fmaf(v, s, acc);
            v = v1; s = s1;
        }
        acc = fmaf(v, s, acc);
    }
    if (RELU) acc = fmaxf(acc, 0.0f);
    dst[(long long)r * O_DIM + t] = (DST_T)acc;
}

// ---------------------------------------------------------------------------
// Fallback atomic path (only if ws too small).
__global__ void spmm1_atomic_kernel(const float* __restrict__ xv,
                                    const int* __restrict__ xr,
                                    const int* __restrict__ xc,
                                    const void* __restrict__ mask,
                                    const float* __restrict__ kern,
                                    const int* __restrict__ flags,
                                    float* __restrict__ h, int nnz) {
    long long gid = (long long)blockIdx.x * blockDim.x + threadIdx.x;
    int e = (int)(gid >> 7);
    if (e >= nnz) return;
    int o = (int)(gid & 127);
    bool keep;
    if (flags[0] == 0)      keep = ((const int*)mask)[e] != 0;
    else if (flags[1] == 0) keep = ((const float*)mask)[e] != 0.0f;
    else                    keep = ((const unsigned char*)mask)[e] != 0;
    if (!keep) return;
    atomicAdd(&h[(long long)xr[e] * O_DIM + o], xv[e] * KEEP_INV * kern[xc[e] * O_DIM + o]);
}

__global__ void spmm2_atomic_kernel(const float* __restrict__ av,
                                    const int* __restrict__ ar,
                                    const int* __restrict__ ac,
                                    const float* __restrict__ h,
                                    float* __restrict__ out, int nnz) {
    long long gid = (long long)blockIdx.x * blockDim.x + threadIdx.x;
    int e = (int)(gid >> 7);
    if (e >= nnz) return;
    int o = (int)(gid & 127);
    atomicAdd(&out[(long long)ar[e] * O_DIM + o], av[e] * h[(long long)ac[e] * O_DIM + o]);
}

__global__ void relu_kernel(float* __restrict__ out, int n4) {
    int stride = gridDim.x * blockDim.x;
    float4* p = (float4*)out;
    for (int i = blockIdx.x * blockDim.x + threadIdx.x; i < n4; i += stride) {
        float4 v = p[i];
        v.x = fmaxf(v.x, 0.0f); v.y = fmaxf(v.y, 0.0f);
        v.z = fmaxf(v.z, 0.0f); v.w = fmaxf(v.w, 0.0f);
        p[i] = v;
    }
}

// ---------------------------------------------------------------------------
static inline size_t align256(size_t x) { return (x + 255) & ~(size_t)255; }

extern "C" void kernel_launch(void* const* d_in, const int* in_sizes, int n_in,
                              void* d_out, int out_size, void* d_ws, size_t ws_size,
                              hipStream_t stream) {
    const float* x_vals   = (const float*)d_in[0];
    const float* kern     = (const float*)d_in[1];   // [256 x 128]
    const float* adj_vals = (const float*)d_in[2];
    const int*   x_rows   = (const int*)d_in[3];
    const int*   x_cols   = (const int*)d_in[4];
    const int*   adj_rows = (const int*)d_in[5];
    const int*   adj_cols = (const int*)d_in[6];
    const void*  mask     = d_in[7];

    const int nnz_x = in_sizes[0];
    const int nnz_a = in_sizes[2];
    const int n_nodes = out_size / O_DIM;
    const int ntot_bins = 2 * n_nodes;
    const long long nnz_tot = (long long)nnz_x + nnz_a;

    float* out = (float*)d_out;
    char* ws = (char*)d_ws;

    // ---- ws carve-up ----
    size_t off = 0;
    int* flags = (int*)d_ws;            off = align256(off + 2 * sizeof(int));
    size_t o_cnt = off;                 off = align256(off + (size_t)ntot_bins * 4);
    size_t o_S = off;                   off = align256(off + ((size_t)ntot_bins + 1) * 4);
    size_t o_cur = off;                 off = align256(off + (size_t)ntot_bins * 4);
    size_t o_bsums = off;               off = align256(off + 4096 * 4);
    size_t o_packed = off;              off = align256(off + (size_t)nnz_tot * 8);
    size_t o_h = off;                   off = align256(off + (size_t)n_nodes * O_DIM * sizeof(half_t));
    const bool csr_ok = (off <= ws_size);

    // mask format detection (both paths need it)
    int scan_words = nnz_x / 4;
    if (scan_words > 16384) scan_words = 16384;
    detect_mask_kernel<<<1, 256, 0, stream>>>((const unsigned int*)mask, scan_words, flags);

    if (csr_ok) {
        int*  cnt    = (int*)(ws + o_cnt);
        int*  S      = (int*)(ws + o_S);
        int*  cursor = (int*)(ws + o_cur);
        int*  bsums  = (int*)(ws + o_bsums);
        int2* packed = (int2*)(ws + o_packed);
        half_t* h    = (half_t*)(ws + o_h);

        hipMemsetAsync(cnt, 0, (size_t)ntot_bins * 4, stream);

        // 1. fused histogram
        {
            long long tot = nnz_tot;
            int blocks = (int)((tot + 255) / 256); if (blocks > 2048) blocks = 2048;
            count_both_kernel<<<blocks, 256, 0, stream>>>(x_rows, nnz_x, adj_rows, nnz_a,
                                                          n_nodes, cnt);
        }
        // 2. 3-phase exclusive scan (writes S and cursor; sentinel S[ntot_bins])
        {
            int nb = (ntot_bins + SCAN_CHUNK - 1) / SCAN_CHUNK;
            scan_partial_kernel<<<nb, SCAN_BS, 0, stream>>>(cnt, ntot_bins, bsums);
            scan_blocksums_kernel<<<1, 1024, 0, stream>>>(bsums, nb, &S[ntot_bins]);
            scan_final_kernel<<<nb, SCAN_BS, 0, stream>>>(cnt, ntot_bins, bsums, S, cursor);
        }
        // 3. fused scatter into packed row-sorted records (dropout folded in)
        {
            long long tot = nnz_tot;
            int blocks = (int)((tot + 255) / 256); if (blocks > 2048) blocks = 2048;
            scatter_both_kernel<<<blocks, 256, 0, stream>>>(x_vals, x_rows, x_cols, mask, flags,
                                                            adj_vals, adj_rows, adj_cols,
                                                            nnz_x, nnz_a, n_nodes,
                                                            cursor, packed);
        }
        // 4. SpMM1: h(f16) = dropout(X) @ kernel
        spmm_csr_kernel<float, half_t, false><<<n_nodes, 128, 0, stream>>>(S, packed, kern, h);
        // 5. SpMM2 + ReLU: out = relu(adj @ h)
        spmm_csr_kernel<half_t, float, true><<<n_nodes, 128, 0, stream>>>(S + n_nodes, packed, h, out);
    } else {
        // ---- fallback: atomic path ----
        float* h = (float*)(ws + 256);
        hipMemsetAsync(h, 0, (size_t)n_nodes * O_DIM * 4, stream);
        hipMemsetAsync(out, 0, (size_t)out_size * 4, stream);
        {
            long long threads = (long long)nnz_x * O_DIM;
            int blocks = (int)((threads + 255) / 256);
            spmm1_atomic_kernel<<<blocks, 256, 0, stream>>>(x_vals, x_rows, x_cols, mask,
                                                            kern, flags, h, nnz_x);
            threads = (long long)nnz_a * O_DIM;
            blocks = (int)((threads + 255) / 256);
            spmm2_atomic_kernel<<<blocks, 256, 0, stream>>>(adj_vals, adj_rows, adj_cols,
                                                            h, out, nnz_a);
        }
        int n4 = out_size / 4;
        int blocks = (n4 + 255) / 256; if (blocks > 2048) blocks = 2048;
        relu_kernel<<<blocks, 256, 0, stream>>>(out, n4);
    }
}